// Round 1
// baseline (357.486 us; speedup 1.0000x reference)
//
#include <hip/hip_runtime.h>
#include <hip/hip_bf16.h>

#define BB 128
#define SS 128
#define EE 1024
#define NQ 8
#define DD 256
#define LL 4
#define MM (BB*SS)

typedef unsigned short bf16s;
typedef __attribute__((ext_vector_type(8))) short bf16x8;
typedef __attribute__((ext_vector_type(4))) float f32x4;

#define AS1 __attribute__((address_space(1)))
#define AS3 __attribute__((address_space(3)))

__device__ __forceinline__ unsigned short f2bf(float x) {
    unsigned u = __float_as_uint(x);
    u += 0x7fffu + ((u >> 16) & 1u);
    return (unsigned short)(u >> 16);
}

// ---------------------------------------------------------------------------
// fp32 RxC -> bf16 CxR transpose-convert (weights)
// ---------------------------------------------------------------------------
__global__ __launch_bounds__(256) void transpose_conv_kernel(
    const float* __restrict__ in, bf16s* __restrict__ out, int R, int C)
{
    __shared__ float t[32][33];
    int bx = blockIdx.x * 32, by = blockIdx.y * 32;
    int lx = threadIdx.x & 31, ly = threadIdx.x >> 5;
#pragma unroll
    for (int i = 0; i < 32; i += 8)
        t[ly + i][lx] = in[(size_t)(by + ly + i) * C + bx + lx];
    __syncthreads();
#pragma unroll
    for (int i = 0; i < 32; i += 8)
        out[(size_t)(bx + ly + i) * R + by + lx] = f2bf(t[lx][ly + i]);
}

// ---------------------------------------------------------------------------
// Wi[1024][8] -> Wit[8][1024] fp32 (tiny; enables coalesced encode loads)
// ---------------------------------------------------------------------------
__global__ __launch_bounds__(256) void wtrans_kernel(
    const float* __restrict__ Wi, float* __restrict__ Wit)
{
    int g = blockIdx.x * 256 + threadIdx.x;   // 0..8191
    int k = g >> 3, j = g & 7;
    Wit[j * 1024 + k] = Wi[g];
}

// ---------------------------------------------------------------------------
// encode: qin = X@Wi+bi; product state v (bf16); Xb = bf16(X) side-product.
// One wave per sample row. All global accesses lane-consecutive (coalesced).
// ---------------------------------------------------------------------------
__global__ __launch_bounds__(256) void encode_kernel(
    const float* __restrict__ X, const float* __restrict__ Wit,
    const float* __restrict__ bi,
    bf16s* __restrict__ Xb, bf16s* __restrict__ v)
{
    const int lane = threadIdx.x & 63;
    const int wid  = threadIdx.x >> 6;
    const int row  = blockIdx.x * 4 + wid;

    const float* xr = X + (size_t)row * EE;
    bf16s* xbr = Xb + (size_t)row * EE;

    float acc[NQ];
#pragma unroll
    for (int j = 0; j < NQ; j++) acc[j] = 0.f;

#pragma unroll
    for (int t = 0; t < 16; t++) {
        int k = t * 64 + lane;
        float x = xr[k];
        xbr[k] = f2bf(x);
#pragma unroll
        for (int j = 0; j < NQ; j++)
            acc[j] += x * Wit[j * 1024 + k];
    }
    float qin[NQ];
#pragma unroll
    for (int j = 0; j < NQ; j++) {
        float s = acc[j];
#pragma unroll
        for (int off = 32; off >= 1; off >>= 1) s += __shfl_xor(s, off, 64);
        qin[j] = s + bi[j];
    }

    // product state: amp[idx] = prod_b (bit_b(idx) ? sin : cos)(qin[7-b]/2)
    float cs[NQ], sn[NQ];
#pragma unroll
    for (int q = 0; q < NQ; q++) __sincosf(0.5f * qin[q], &sn[q], &cs[q]);

    float common = 1.f;
#pragma unroll
    for (int b = 2; b < 8; b++) {
        int q = 7 - b;
        common *= ((lane >> (b - 2)) & 1) ? sn[q] : cs[q];
    }
    // cc bit0 -> qubit 7, bit1 -> qubit 6
    float a0 = common * cs[6] * cs[7];
    float a1 = common * cs[6] * sn[7];
    float a2 = common * sn[6] * cs[7];
    float a3 = common * sn[6] * sn[7];
    ushort4 vo;
    vo.x = f2bf(a0); vo.y = f2bf(a1); vo.z = f2bf(a2); vo.w = f2bf(a3);
    ((ushort4*)(v + (size_t)row * DD))[lane] = vo;
}

// ---------------------------------------------------------------------------
// ubuild: simulate the theta-circuit on all 256 basis states -> Ubt bf16.
// Ubt[n][j] (n<256: U_re[n][j]; n>=256: U_im[n-256][j]), j = basis column.
// ---------------------------------------------------------------------------
__global__ __launch_bounds__(256) void ubuild_kernel(
    const float* __restrict__ theta, bf16s* __restrict__ Ubt)
{
    const int lane = threadIdx.x & 63;
    const int wid  = threadIdx.x >> 6;
    const int col  = blockIdx.x * 4 + wid;   // 0..255

    float sr[4], si[4];
#pragma unroll
    for (int c = 0; c < 4; c++) { sr[c] = 0.f; si[c] = 0.f; }
    if (lane == (col >> 2)) sr[col & 3] = 1.f;

    auto apply_ry = [&](int b, float th) {
        float s, c;
        __sincosf(0.5f * th, &s, &c);
        if (b >= 2) {
            int lb = b - 2;
            int bit = (lane >> lb) & 1;
            float sgn = bit ? s : -s;
#pragma unroll
            for (int cc = 0; cc < 4; cc++) {
                float pr = __shfl_xor(sr[cc], 1 << lb, 64);
                float pi = __shfl_xor(si[cc], 1 << lb, 64);
                sr[cc] = c * sr[cc] + sgn * pr;
                si[cc] = c * si[cc] + sgn * pi;
            }
        } else {
            int m = 1 << b;
            float tr[4], ti[4];
#pragma unroll
            for (int cc = 0; cc < 4; cc++) { tr[cc] = sr[cc]; ti[cc] = si[cc]; }
#pragma unroll
            for (int cc = 0; cc < 4; cc++) {
                int bit = (cc >> b) & 1;
                float sgn = bit ? s : -s;
                sr[cc] = c * tr[cc] + sgn * tr[cc ^ m];
                si[cc] = c * ti[cc] + sgn * ti[cc ^ m];
            }
        }
    };
    auto apply_rz = [&](int b, float th) {
        float sz, cr;
        __sincosf(0.5f * th, &sz, &cr);
#pragma unroll
        for (int cc = 0; cc < 4; cc++) {
            int bit = (b >= 2) ? ((lane >> (b - 2)) & 1) : ((cc >> b) & 1);
            float ci = bit ? sz : -sz;
            float r = sr[cc], i = si[cc];
            sr[cc] = r * cr - i * ci;
            si[cc] = r * ci + i * cr;
        }
    };
    auto apply_cnot = [&](int bc, int bt) {
        float pr[4], pi[4];
        if (bt >= 2) {
            int m = 1 << (bt - 2);
#pragma unroll
            for (int cc = 0; cc < 4; cc++) {
                pr[cc] = __shfl_xor(sr[cc], m, 64);
                pi[cc] = __shfl_xor(si[cc], m, 64);
            }
        } else {
            int m = 1 << bt;
#pragma unroll
            for (int cc = 0; cc < 4; cc++) {
                pr[cc] = sr[cc ^ m];
                pi[cc] = si[cc ^ m];
            }
        }
#pragma unroll
        for (int cc = 0; cc < 4; cc++) {
            int ctrl = (bc >= 2) ? ((lane >> (bc - 2)) & 1) : ((cc >> bc) & 1);
            sr[cc] = ctrl ? pr[cc] : sr[cc];
            si[cc] = ctrl ? pi[cc] : si[cc];
        }
    };

#pragma unroll
    for (int l = 0; l < LL; l++) {
#pragma unroll
        for (int q = 0; q < NQ; q++) {
            apply_ry(7 - q, theta[(l * NQ + q) * 2 + 0]);
            apply_rz(7 - q, theta[(l * NQ + q) * 2 + 1]);
        }
#pragma unroll
        for (int q = 0; q < NQ; q++) {
            int t = (q + 1) & 7;
            apply_cnot(7 - q, 7 - t);
        }
    }

#pragma unroll
    for (int cc = 0; cc < 4; cc++) {
        int i = lane * 4 + cc;
        Ubt[(size_t)i * DD + col]         = f2bf(sr[cc]);
        Ubt[(size_t)(i + DD) * DD + col]  = f2bf(si[cc]);
    }
}

// ---------------------------------------------------------------------------
// psi_gemm: C[s][n] = v[s][:] . Ubt[n][:]  (M=16384, N=512, K=256)
// Epilogue writes P1[s][n] = C, and P2: n<256 -> P2[s][n+256] = -C,
// n>=256 -> P2[s][n-256] = C.
// ---------------------------------------------------------------------------
__global__ __launch_bounds__(256) void psi_gemm_kernel(
    const bf16s* __restrict__ A, const bf16s* __restrict__ Bt,
    bf16s* __restrict__ P1, bf16s* __restrict__ P2)
{
    __shared__ bf16s As[128 * 32];
    __shared__ bf16s Bs[128 * 32];

    const int tid  = threadIdx.x;
    const int wave = tid >> 6, lane = tid & 63;
    const int quad = lane >> 4, lr = lane & 15;
    const int wm = (wave >> 1) * 64, wn = (wave & 1) * 64;
    const int m0 = blockIdx.x * 128, n0 = blockIdx.y * 128;
    const int K = DD, N = 2 * DD;

    f32x4 acc[4][4];
#pragma unroll
    for (int i = 0; i < 4; i++)
#pragma unroll
        for (int j = 0; j < 4; j++) acc[i][j] = (f32x4){0.f, 0.f, 0.f, 0.f};

    for (int kt = 0; kt < K; kt += 32) {
#pragma unroll
        for (int j = 0; j < 2; j++) {
            int ch = j * 256 + tid;
            int row = ch >> 2, kc = (ch & 3) * 8;
            __builtin_amdgcn_global_load_lds(
                (AS1 const void*)(A + (size_t)(m0 + row) * K + kt + kc),
                (AS3 void*)(As + (size_t)(j * 256 + wave * 64) * 8), 16, 0, 0);
            __builtin_amdgcn_global_load_lds(
                (AS1 const void*)(Bt + (size_t)(n0 + row) * K + kt + kc),
                (AS3 void*)(Bs + (size_t)(j * 256 + wave * 64) * 8), 16, 0, 0);
        }
        __syncthreads();

        bf16x8 af[4], bfr[4];
#pragma unroll
        for (int i = 0; i < 4; i++)
            af[i] = *(const bf16x8*)(As + (wm + i * 16 + lr) * 32 + quad * 8);
#pragma unroll
        for (int j = 0; j < 4; j++)
            bfr[j] = *(const bf16x8*)(Bs + (wn + j * 16 + lr) * 32 + quad * 8);
#pragma unroll
        for (int i = 0; i < 4; i++)
#pragma unroll
            for (int j = 0; j < 4; j++)
                acc[i][j] = __builtin_amdgcn_mfma_f32_16x16x32_bf16(
                    af[i], bfr[j], acc[i][j], 0, 0, 0);
        __syncthreads();
    }

#pragma unroll
    for (int i = 0; i < 4; i++) {
        int row0 = m0 + wm + i * 16 + quad * 4;
#pragma unroll
        for (int j = 0; j < 4; j++) {
            int col = n0 + wn + j * 16 + lr;
            int c2  = (col < DD) ? (col + DD) : (col - DD);
            float sgn = (col < DD) ? -1.f : 1.f;
#pragma unroll
            for (int r = 0; r < 4; r++) {
                float val = acc[i][j][r];
                P1[(size_t)(row0 + r) * N + col] = f2bf(val);
                P2[(size_t)(row0 + r) * N + c2] = f2bf(sgn * val);
            }
        }
    }
}

// ---------------------------------------------------------------------------
// MFMA bf16 GEMM: C[M][N] = A[M][K] @ Bt[N][K]^T (+bias[col]). m97-style.
// ---------------------------------------------------------------------------
template<bool OUT_BF16>
__global__ __launch_bounds__(256) void mfma_gemm(
    const bf16s* __restrict__ A, const bf16s* __restrict__ Bt,
    const float* __restrict__ bias, void* __restrict__ Cv,
    int M, int N, int K,
    long long sA, long long sB, long long sC)
{
    __shared__ bf16s As[128 * 32];
    __shared__ bf16s Bs[128 * 32];

    const int tid  = threadIdx.x;
    const int wave = tid >> 6, lane = tid & 63;
    const int quad = lane >> 4, lr = lane & 15;
    const int wm = (wave >> 1) * 64, wn = (wave & 1) * 64;
    const int m0 = blockIdx.x * 128, n0 = blockIdx.y * 128;

    A  += (size_t)blockIdx.z * sA;
    Bt += (size_t)blockIdx.z * sB;

    f32x4 acc[4][4];
#pragma unroll
    for (int i = 0; i < 4; i++)
#pragma unroll
        for (int j = 0; j < 4; j++) acc[i][j] = (f32x4){0.f, 0.f, 0.f, 0.f};

    for (int kt = 0; kt < K; kt += 32) {
#pragma unroll
        for (int j = 0; j < 2; j++) {
            int ch = j * 256 + tid;
            int row = ch >> 2, kc = (ch & 3) * 8;
            __builtin_amdgcn_global_load_lds(
                (AS1 const void*)(A + (size_t)(m0 + row) * K + kt + kc),
                (AS3 void*)(As + (size_t)(j * 256 + wave * 64) * 8), 16, 0, 0);
            __builtin_amdgcn_global_load_lds(
                (AS1 const void*)(Bt + (size_t)(n0 + row) * K + kt + kc),
                (AS3 void*)(Bs + (size_t)(j * 256 + wave * 64) * 8), 16, 0, 0);
        }
        __syncthreads();

        bf16x8 af[4], bfr[4];
#pragma unroll
        for (int i = 0; i < 4; i++)
            af[i] = *(const bf16x8*)(As + (wm + i * 16 + lr) * 32 + quad * 8);
#pragma unroll
        for (int j = 0; j < 4; j++)
            bfr[j] = *(const bf16x8*)(Bs + (wn + j * 16 + lr) * 32 + quad * 8);
#pragma unroll
        for (int i = 0; i < 4; i++)
#pragma unroll
            for (int j = 0; j < 4; j++)
                acc[i][j] = __builtin_amdgcn_mfma_f32_16x16x32_bf16(
                    af[i], bfr[j], acc[i][j], 0, 0, 0);
        __syncthreads();
    }

    float* Cf = (float*)Cv + (size_t)blockIdx.z * sC;
    bf16s* Cb = (bf16s*)Cv + (size_t)blockIdx.z * sC;
#pragma unroll
    for (int i = 0; i < 4; i++) {
        int row0 = m0 + wm + i * 16 + quad * 4;
#pragma unroll
        for (int j = 0; j < 4; j++) {
            int col = n0 + wn + j * 16 + lr;
            float bb = bias ? bias[col] : 0.f;
#pragma unroll
            for (int r = 0; r < 4; r++) {
                float v = acc[i][j][r] + bb;
                if (OUT_BF16) Cb[(size_t)(row0 + r) * N + col] = f2bf(v);
                else          Cf[(size_t)(row0 + r) * N + col] = v;
            }
        }
    }
}

// ---------------------------------------------------------------------------
// attn: MFMA Gram + fused softmax.
// ---------------------------------------------------------------------------
__global__ __launch_bounds__(256) void attn_kernel(
    const bf16s* __restrict__ P1, const bf16s* __restrict__ P2,
    const float* __restrict__ phi,
    float* __restrict__ attn, bf16s* __restrict__ attn_bf)
{
    __shared__ bf16s As [64 * 32];
    __shared__ bf16s Bs1[128 * 32];
    __shared__ bf16s Bs2[128 * 32];

    const int tid  = threadIdx.x;
    const int wave = tid >> 6, lane = tid & 63;
    const int quad = lane >> 4, lr = lane & 15;
    const int b = blockIdx.y;
    const int s0 = blockIdx.x * 64;
    const bf16s* p1b = P1 + (size_t)b * 128 * 512;
    const bf16s* p2b = P2 + (size_t)b * 128 * 512;

    f32x4 accre[8], accim[8];
#pragma unroll
    for (int j = 0; j < 8; j++) {
        accre[j] = (f32x4){0.f, 0.f, 0.f, 0.f};
        accim[j] = (f32x4){0.f, 0.f, 0.f, 0.f};
    }

    for (int kt = 0; kt < 512; kt += 32) {
        {
            int row = tid >> 2, kc = (tid & 3) * 8;
            __builtin_amdgcn_global_load_lds(
                (AS1 const void*)(p1b + (size_t)(s0 + row) * 512 + kt + kc),
                (AS3 void*)(As + (size_t)(wave * 64) * 8), 16, 0, 0);
        }
#pragma unroll
        for (int j = 0; j < 2; j++) {
            int ch = j * 256 + tid;
            int row = ch >> 2, kc = (ch & 3) * 8;
            __builtin_amdgcn_global_load_lds(
                (AS1 const void*)(p1b + (size_t)row * 512 + kt + kc),
                (AS3 void*)(Bs1 + (size_t)(j * 256 + wave * 64) * 8), 16, 0, 0);
            __builtin_amdgcn_global_load_lds(
                (AS1 const void*)(p2b + (size_t)row * 512 + kt + kc),
                (AS3 void*)(Bs2 + (size_t)(j * 256 + wave * 64) * 8), 16, 0, 0);
        }
        __syncthreads();

        bf16x8 afr = *(const bf16x8*)(As + (wave * 16 + lr) * 32 + quad * 8);
#pragma unroll
        for (int j = 0; j < 8; j++) {
            bf16x8 b1 = *(const bf16x8*)(Bs1 + (j * 16 + lr) * 32 + quad * 8);
            accre[j] = __builtin_amdgcn_mfma_f32_16x16x32_bf16(afr, b1, accre[j], 0, 0, 0);
            bf16x8 b2 = *(const bf16x8*)(Bs2 + (j * 16 + lr) * 32 + quad * 8);
            accim[j] = __builtin_amdgcn_mfma_f32_16x16x32_bf16(afr, b2, accim[j], 0, 0, 0);
        }
        __syncthreads();
    }

    const float isq = 0.35355339059327373f;
    float ph_r[4], ph_c[8];
#pragma unroll
    for (int r = 0; r < 4; r++) ph_r[r] = phi[s0 + wave * 16 + quad * 4 + r];
#pragma unroll
    for (int j = 0; j < 8; j++) ph_c[j] = phi[j * 16 + lr];

#pragma unroll
    for (int r = 0; r < 4; r++) {
        float v[8];
        float mx = -1e30f;
#pragma unroll
        for (int j = 0; j < 8; j++) {
            float re = accre[j][r], im = accim[j][r];
            v[j] = (re * re + im * im) * isq + __cosf(ph_c[j] - ph_r[r]);
            mx = fmaxf(mx, v[j]);
        }
#pragma unroll
        for (int off = 1; off <= 8; off <<= 1) mx = fmaxf(mx, __shfl_xor(mx, off, 64));
        float sm = 0.f;
#pragma unroll
        for (int j = 0; j < 8; j++) { v[j] = __expf(v[j] - mx); sm += v[j]; }
#pragma unroll
        for (int off = 1; off <= 8; off <<= 1) sm += __shfl_xor(sm, off, 64);
        float inv = 1.f / sm;
        int srow = b * 128 + s0 + wave * 16 + quad * 4 + r;
#pragma unroll
        for (int j = 0; j < 8; j++) {
            float o = v[j] * inv;
            attn[(size_t)srow * 128 + j * 16 + lr] = o;
            attn_bf[(size_t)srow * 128 + j * 16 + lr] = f2bf(o);
        }
    }
}

// ---------------------------------------------------------------------------
extern "C" void kernel_launch(void* const* d_in, const int* in_sizes, int n_in,
                              void* d_out, int out_size, void* d_ws, size_t ws_size,
                              hipStream_t stream) {
    const float* X     = (const float*)d_in[0];
    const float* Wi    = (const float*)d_in[1];
    const float* bi    = (const float*)d_in[2];
    const float* Wv    = (const float*)d_in[3];
    const float* bv    = (const float*)d_in[4];
    const float* Wo    = (const float*)d_in[5];
    const float* bo    = (const float*)d_in[6];
    const float* theta = (const float*)d_in[7];
    const float* phi   = (const float*)d_in[8];

    float* y    = (float*)d_out;
    float* attn = y + (size_t)MM * EE;

    bf16s* Xb   = (bf16s*)d_ws;                      // 16384*1024
    bf16s* P1   = Xb  + (size_t)MM * EE;             // 16384*512
    bf16s* P2   = P1  + (size_t)MM * 512;            // 16384*512
    bf16s* Vtb  = P2  + (size_t)MM * 512;            // 128 * 1024*128
    bf16s* o2b  = Vtb + (size_t)MM * EE;             // 16384*1024
    bf16s* abf  = o2b + (size_t)MM * EE;             // 128*128*128
    bf16s* Wvt  = abf + (size_t)BB * SS * SS;        // 1024*1024
    bf16s* Wot  = Wvt + (size_t)EE * EE;             // 1024*1024
    float* Wit  = (float*)(Wot + (size_t)EE * EE);   // 8*1024 fp32 (32 KB)
    // v and Ubt overlap o2b (o2b written only after v/Ubt are dead)
    bf16s* v    = o2b;                               // 16384*256
    bf16s* Ubt  = o2b + (size_t)MM * DD;             // 512*256

    // Wi transpose (coalesced encode loads)
    wtrans_kernel<<<32, 256, 0, stream>>>(Wi, Wit);
    // encode: qin -> product state v (bf16) + Xb side-product
    encode_kernel<<<MM / 4, 256, 0, stream>>>(X, Wit, bi, Xb, v);
    // build circuit unitary (theta only)
    ubuild_kernel<<<64, 256, 0, stream>>>(theta, Ubt);
    // weight transposes
    transpose_conv_kernel<<<dim3(32, 32), 256, 0, stream>>>(Wv, Wvt, EE, EE);
    transpose_conv_kernel<<<dim3(32, 32), 256, 0, stream>>>(Wo, Wot, EE, EE);
    // psi = v @ Ubt^T -> P1, P2
    psi_gemm_kernel<<<dim3(MM / 128, 4), 256, 0, stream>>>(v, Ubt, P1, P2);
    // Vt_b = Wv^T @ X_b^T
    mfma_gemm<true><<<dim3(EE / 128, 1, BB), 256, 0, stream>>>(
        Wvt, Xb, nullptr, Vtb, EE, SS, EE,
        0, (long long)SS * EE, (long long)EE * SS);
    // attn (Gram via MFMA + softmax)
    attn_kernel<<<dim3(2, BB), 256, 0, stream>>>(P1, P2, phi, attn, abf);
    // o2_b = attn_b @ V_b + bv
    mfma_gemm<true><<<dim3(1, EE / 128, BB), 256, 0, stream>>>(
        abf, Vtb, bv, o2b, SS, EE, SS,
        (long long)SS * SS, (long long)EE * SS, (long long)SS * EE);
    // y = o2 @ Wo + bo
    mfma_gemm<false><<<dim3(MM / 128, EE / 128, 1), 256, 0, stream>>>(
        o2b, Wot, bo, y, MM, EE, EE, 0, 0, 0);
}

// Round 2
// 352.325 us; speedup vs baseline: 1.0146x; 1.0146x over previous
//
#include <hip/hip_runtime.h>
#include <hip/hip_bf16.h>

#define BB 128
#define SS 128
#define EE 1024
#define NQ 8
#define DD 256
#define LL 4
#define MM (BB*SS)

typedef unsigned short bf16s;
typedef __attribute__((ext_vector_type(8))) short bf16x8;
typedef __attribute__((ext_vector_type(4))) float f32x4;

#define AS1 __attribute__((address_space(1)))
#define AS3 __attribute__((address_space(3)))

__device__ __forceinline__ unsigned short f2bf(float x) {
    unsigned u = __float_as_uint(x);
    u += 0x7fffu + ((u >> 16) & 1u);
    return (unsigned short)(u >> 16);
}

// ---------------------------------------------------------------------------
// fp32 RxC -> bf16 CxR transpose-convert (weights)
// ---------------------------------------------------------------------------
__global__ __launch_bounds__(256) void transpose_conv_kernel(
    const float* __restrict__ in, bf16s* __restrict__ out, int R, int C)
{
    __shared__ float t[32][33];
    int bx = blockIdx.x * 32, by = blockIdx.y * 32;
    int lx = threadIdx.x & 31, ly = threadIdx.x >> 5;
#pragma unroll
    for (int i = 0; i < 32; i += 8)
        t[ly + i][lx] = in[(size_t)(by + ly + i) * C + bx + lx];
    __syncthreads();
#pragma unroll
    for (int i = 0; i < 32; i += 8)
        out[(size_t)(bx + ly + i) * R + by + lx] = f2bf(t[lx][ly + i]);
}

// ---------------------------------------------------------------------------
// Wi[1024][8] -> Wit[8][1024] fp32 (tiny; enables coalesced encode loads)
// ---------------------------------------------------------------------------
__global__ __launch_bounds__(256) void wtrans_kernel(
    const float* __restrict__ Wi, float* __restrict__ Wit)
{
    int g = blockIdx.x * 256 + threadIdx.x;   // 0..8191
    int k = g >> 3, j = g & 7;
    Wit[j * 1024 + k] = Wi[g];
}

// ---------------------------------------------------------------------------
// encode: qin = X@Wi+bi; product state v (bf16); Xb = bf16(X) side-product.
// One wave per sample row. float4-vectorized (16B/lane) global loads.
// ---------------------------------------------------------------------------
__global__ __launch_bounds__(256) void encode_kernel(
    const float* __restrict__ X, const float* __restrict__ Wit,
    const float* __restrict__ bi,
    bf16s* __restrict__ Xb, bf16s* __restrict__ v)
{
    const int lane = threadIdx.x & 63;
    const int wid  = threadIdx.x >> 6;
    const int row  = blockIdx.x * 4 + wid;

    const f32x4* xr4 = (const f32x4*)(X + (size_t)row * EE);
    ushort4* xbr4 = (ushort4*)(Xb + (size_t)row * EE);

    float acc[NQ];
#pragma unroll
    for (int j = 0; j < NQ; j++) acc[j] = 0.f;

#pragma unroll
    for (int t = 0; t < 4; t++) {
        int k4 = t * 64 + lane;          // float4 index within the row
        f32x4 x = xr4[k4];
        ushort4 xb;
        xb.x = f2bf(x[0]); xb.y = f2bf(x[1]);
        xb.z = f2bf(x[2]); xb.w = f2bf(x[3]);
        xbr4[k4] = xb;
#pragma unroll
        for (int j = 0; j < NQ; j++) {
            f32x4 w = ((const f32x4*)(Wit + j * 1024))[k4];
            acc[j] += x[0]*w[0] + x[1]*w[1] + x[2]*w[2] + x[3]*w[3];
        }
    }
    float qin[NQ];
#pragma unroll
    for (int j = 0; j < NQ; j++) {
        float s = acc[j];
#pragma unroll
        for (int off = 32; off >= 1; off >>= 1) s += __shfl_xor(s, off, 64);
        qin[j] = s + bi[j];
    }

    // product state: amp[idx] = prod_b (bit_b(idx) ? sin : cos)(qin[7-b]/2)
    float cs[NQ], sn[NQ];
#pragma unroll
    for (int q = 0; q < NQ; q++) __sincosf(0.5f * qin[q], &sn[q], &cs[q]);

    float common = 1.f;
#pragma unroll
    for (int b = 2; b < 8; b++) {
        int q = 7 - b;
        common *= ((lane >> (b - 2)) & 1) ? sn[q] : cs[q];
    }
    // cc bit0 -> qubit 7, bit1 -> qubit 6
    float a0 = common * cs[6] * cs[7];
    float a1 = common * cs[6] * sn[7];
    float a2 = common * sn[6] * cs[7];
    float a3 = common * sn[6] * sn[7];
    ushort4 vo;
    vo.x = f2bf(a0); vo.y = f2bf(a1); vo.z = f2bf(a2); vo.w = f2bf(a3);
    ((ushort4*)(v + (size_t)row * DD))[lane] = vo;
}

// ---------------------------------------------------------------------------
// ubuild: simulate the theta-circuit on all 256 basis states -> Ubt bf16.
// Ubt[n][j] (n<256: U_re[n][j]; n>=256: U_im[n-256][j]), j = basis column.
// ---------------------------------------------------------------------------
__global__ __launch_bounds__(256) void ubuild_kernel(
    const float* __restrict__ theta, bf16s* __restrict__ Ubt)
{
    const int lane = threadIdx.x & 63;
    const int wid  = threadIdx.x >> 6;
    const int col  = blockIdx.x * 4 + wid;   // 0..255

    float sr[4], si[4];
#pragma unroll
    for (int c = 0; c < 4; c++) { sr[c] = 0.f; si[c] = 0.f; }
    if (lane == (col >> 2)) sr[col & 3] = 1.f;

    auto apply_ry = [&](int b, float th) {
        float s, c;
        __sincosf(0.5f * th, &s, &c);
        if (b >= 2) {
            int lb = b - 2;
            int bit = (lane >> lb) & 1;
            float sgn = bit ? s : -s;
#pragma unroll
            for (int cc = 0; cc < 4; cc++) {
                float pr = __shfl_xor(sr[cc], 1 << lb, 64);
                float pi = __shfl_xor(si[cc], 1 << lb, 64);
                sr[cc] = c * sr[cc] + sgn * pr;
                si[cc] = c * si[cc] + sgn * pi;
            }
        } else {
            int m = 1 << b;
            float tr[4], ti[4];
#pragma unroll
            for (int cc = 0; cc < 4; cc++) { tr[cc] = sr[cc]; ti[cc] = si[cc]; }
#pragma unroll
            for (int cc = 0; cc < 4; cc++) {
                int bit = (cc >> b) & 1;
                float sgn = bit ? s : -s;
                sr[cc] = c * tr[cc] + sgn * tr[cc ^ m];
                si[cc] = c * ti[cc] + sgn * ti[cc ^ m];
            }
        }
    };
    auto apply_rz = [&](int b, float th) {
        float sz, cr;
        __sincosf(0.5f * th, &sz, &cr);
#pragma unroll
        for (int cc = 0; cc < 4; cc++) {
            int bit = (b >= 2) ? ((lane >> (b - 2)) & 1) : ((cc >> b) & 1);
            float ci = bit ? sz : -sz;
            float r = sr[cc], i = si[cc];
            sr[cc] = r * cr - i * ci;
            si[cc] = r * ci + i * cr;
        }
    };
    auto apply_cnot = [&](int bc, int bt) {
        float pr[4], pi[4];
        if (bt >= 2) {
            int m = 1 << (bt - 2);
#pragma unroll
            for (int cc = 0; cc < 4; cc++) {
                pr[cc] = __shfl_xor(sr[cc], m, 64);
                pi[cc] = __shfl_xor(si[cc], m, 64);
            }
        } else {
            int m = 1 << bt;
#pragma unroll
            for (int cc = 0; cc < 4; cc++) {
                pr[cc] = sr[cc ^ m];
                pi[cc] = si[cc ^ m];
            }
        }
#pragma unroll
        for (int cc = 0; cc < 4; cc++) {
            int ctrl = (bc >= 2) ? ((lane >> (bc - 2)) & 1) : ((cc >> bc) & 1);
            sr[cc] = ctrl ? pr[cc] : sr[cc];
            si[cc] = ctrl ? pi[cc] : si[cc];
        }
    };

#pragma unroll
    for (int l = 0; l < LL; l++) {
#pragma unroll
        for (int q = 0; q < NQ; q++) {
            apply_ry(7 - q, theta[(l * NQ + q) * 2 + 0]);
            apply_rz(7 - q, theta[(l * NQ + q) * 2 + 1]);
        }
#pragma unroll
        for (int q = 0; q < NQ; q++) {
            int t = (q + 1) & 7;
            apply_cnot(7 - q, 7 - t);
        }
    }

#pragma unroll
    for (int cc = 0; cc < 4; cc++) {
        int i = lane * 4 + cc;
        Ubt[(size_t)i * DD + col]         = f2bf(sr[cc]);
        Ubt[(size_t)(i + DD) * DD + col]  = f2bf(si[cc]);
    }
}

// ---------------------------------------------------------------------------
// psi_gemm: C[s][n] = v[s][:] . Ubt[n][:]  (M=16384, N=512, K=256)
// 2-phase double-buffered pipeline. Epilogue writes P1/P2.
// ---------------------------------------------------------------------------
__global__ __launch_bounds__(256) void psi_gemm_kernel(
    const bf16s* __restrict__ A, const bf16s* __restrict__ Bt,
    bf16s* __restrict__ P1, bf16s* __restrict__ P2)
{
    __shared__ bf16s As[2][128 * 32];
    __shared__ bf16s Bs[2][128 * 32];

    const int tid  = threadIdx.x;
    const int wave = tid >> 6, lane = tid & 63;
    const int quad = lane >> 4, lr = lane & 15;
    const int wm = (wave >> 1) * 64, wn = (wave & 1) * 64;
    const int m0 = blockIdx.x * 128, n0 = blockIdx.y * 128;
    const int K = DD, N = 2 * DD;

    f32x4 acc[4][4];
#pragma unroll
    for (int i = 0; i < 4; i++)
#pragma unroll
        for (int j = 0; j < 4; j++) acc[i][j] = (f32x4){0.f, 0.f, 0.f, 0.f};

    auto stage = [&](int buf, int kt) {
#pragma unroll
        for (int j = 0; j < 2; j++) {
            int ch = j * 256 + tid;
            int row = ch >> 2, kc = (ch & 3) * 8;
            __builtin_amdgcn_global_load_lds(
                (AS1 const void*)(A + (size_t)(m0 + row) * K + kt + kc),
                (AS3 void*)(As[buf] + (size_t)(j * 256 + wave * 64) * 8), 16, 0, 0);
            __builtin_amdgcn_global_load_lds(
                (AS1 const void*)(Bt + (size_t)(n0 + row) * K + kt + kc),
                (AS3 void*)(Bs[buf] + (size_t)(j * 256 + wave * 64) * 8), 16, 0, 0);
        }
    };
    auto compute = [&](int buf) {
        bf16x8 af[4], bfr[4];
#pragma unroll
        for (int i = 0; i < 4; i++)
            af[i] = *(const bf16x8*)(As[buf] + (wm + i * 16 + lr) * 32 + quad * 8);
#pragma unroll
        for (int j = 0; j < 4; j++)
            bfr[j] = *(const bf16x8*)(Bs[buf] + (wn + j * 16 + lr) * 32 + quad * 8);
#pragma unroll
        for (int i = 0; i < 4; i++)
#pragma unroll
            for (int j = 0; j < 4; j++)
                acc[i][j] = __builtin_amdgcn_mfma_f32_16x16x32_bf16(
                    af[i], bfr[j], acc[i][j], 0, 0, 0);
    };

    const int nt = K >> 5;   // 8 (even)
    stage(0, 0);
    __syncthreads();
    for (int t = 0; t < nt - 2; t += 2) {
        stage(1, (t + 1) << 5);
        compute(0);
        __syncthreads();
        stage(0, (t + 2) << 5);
        compute(1);
        __syncthreads();
    }
    stage(1, (nt - 1) << 5);
    compute(0);
    __syncthreads();
    compute(1);

#pragma unroll
    for (int i = 0; i < 4; i++) {
        int row0 = m0 + wm + i * 16 + quad * 4;
#pragma unroll
        for (int j = 0; j < 4; j++) {
            int col = n0 + wn + j * 16 + lr;
            int c2  = (col < DD) ? (col + DD) : (col - DD);
            float sgn = (col < DD) ? -1.f : 1.f;
#pragma unroll
            for (int r = 0; r < 4; r++) {
                float val = acc[i][j][r];
                P1[(size_t)(row0 + r) * N + col] = f2bf(val);
                P2[(size_t)(row0 + r) * N + c2] = f2bf(sgn * val);
            }
        }
    }
}

// ---------------------------------------------------------------------------
// MFMA bf16 GEMM: C[M][N] = A[M][K] @ Bt[N][K]^T (+bias[col]).
// 2-phase double-buffered pipeline. SWAPXY: N-tile from blockIdx.x (fastest)
// so consecutive blocks share the A-tile (L2/L3 locality for wide-M GEMMs).
// ---------------------------------------------------------------------------
template<bool OUT_BF16, bool SWAPXY>
__global__ __launch_bounds__(256) void mfma_gemm(
    const bf16s* __restrict__ A, const bf16s* __restrict__ Bt,
    const float* __restrict__ bias, void* __restrict__ Cv,
    int M, int N, int K,
    long long sA, long long sB, long long sC)
{
    __shared__ bf16s As[2][128 * 32];
    __shared__ bf16s Bs[2][128 * 32];

    const int tid  = threadIdx.x;
    const int wave = tid >> 6, lane = tid & 63;
    const int quad = lane >> 4, lr = lane & 15;
    const int wm = (wave >> 1) * 64, wn = (wave & 1) * 64;
    const int m0 = (SWAPXY ? blockIdx.y : blockIdx.x) * 128;
    const int n0 = (SWAPXY ? blockIdx.x : blockIdx.y) * 128;

    A  += (size_t)blockIdx.z * sA;
    Bt += (size_t)blockIdx.z * sB;

    f32x4 acc[4][4];
#pragma unroll
    for (int i = 0; i < 4; i++)
#pragma unroll
        for (int j = 0; j < 4; j++) acc[i][j] = (f32x4){0.f, 0.f, 0.f, 0.f};

    auto stage = [&](int buf, int kt) {
#pragma unroll
        for (int j = 0; j < 2; j++) {
            int ch = j * 256 + tid;
            int row = ch >> 2, kc = (ch & 3) * 8;
            __builtin_amdgcn_global_load_lds(
                (AS1 const void*)(A + (size_t)(m0 + row) * K + kt + kc),
                (AS3 void*)(As[buf] + (size_t)(j * 256 + wave * 64) * 8), 16, 0, 0);
            __builtin_amdgcn_global_load_lds(
                (AS1 const void*)(Bt + (size_t)(n0 + row) * K + kt + kc),
                (AS3 void*)(Bs[buf] + (size_t)(j * 256 + wave * 64) * 8), 16, 0, 0);
        }
    };
    auto compute = [&](int buf) {
        bf16x8 af[4], bfr[4];
#pragma unroll
        for (int i = 0; i < 4; i++)
            af[i] = *(const bf16x8*)(As[buf] + (wm + i * 16 + lr) * 32 + quad * 8);
#pragma unroll
        for (int j = 0; j < 4; j++)
            bfr[j] = *(const bf16x8*)(Bs[buf] + (wn + j * 16 + lr) * 32 + quad * 8);
#pragma unroll
        for (int i = 0; i < 4; i++)
#pragma unroll
            for (int j = 0; j < 4; j++)
                acc[i][j] = __builtin_amdgcn_mfma_f32_16x16x32_bf16(
                    af[i], bfr[j], acc[i][j], 0, 0, 0);
    };

    const int nt = K >> 5;   // all call sites: even, >= 4
    stage(0, 0);
    __syncthreads();
    for (int t = 0; t < nt - 2; t += 2) {
        stage(1, (t + 1) << 5);
        compute(0);
        __syncthreads();
        stage(0, (t + 2) << 5);
        compute(1);
        __syncthreads();
    }
    stage(1, (nt - 1) << 5);
    compute(0);
    __syncthreads();
    compute(1);

    float* Cf = (float*)Cv + (size_t)blockIdx.z * sC;
    bf16s* Cb = (bf16s*)Cv + (size_t)blockIdx.z * sC;
#pragma unroll
    for (int i = 0; i < 4; i++) {
        int row0 = m0 + wm + i * 16 + quad * 4;
#pragma unroll
        for (int j = 0; j < 4; j++) {
            int col = n0 + wn + j * 16 + lr;
            float bb = bias ? bias[col] : 0.f;
#pragma unroll
            for (int r = 0; r < 4; r++) {
                float v = acc[i][j][r] + bb;
                if (OUT_BF16) Cb[(size_t)(row0 + r) * N + col] = f2bf(v);
                else          Cf[(size_t)(row0 + r) * N + col] = v;
            }
        }
    }
}

// ---------------------------------------------------------------------------
// attn: MFMA Gram + fused softmax. 2-phase double-buffered pipeline.
// ---------------------------------------------------------------------------
__global__ __launch_bounds__(256) void attn_kernel(
    const bf16s* __restrict__ P1, const bf16s* __restrict__ P2,
    const float* __restrict__ phi,
    float* __restrict__ attn, bf16s* __restrict__ attn_bf)
{
    __shared__ bf16s As [2][64 * 32];
    __shared__ bf16s Bs1[2][128 * 32];
    __shared__ bf16s Bs2[2][128 * 32];

    const int tid  = threadIdx.x;
    const int wave = tid >> 6, lane = tid & 63;
    const int quad = lane >> 4, lr = lane & 15;
    const int b = blockIdx.y;
    const int s0 = blockIdx.x * 64;
    const bf16s* p1b = P1 + (size_t)b * 128 * 512;
    const bf16s* p2b = P2 + (size_t)b * 128 * 512;

    f32x4 accre[8], accim[8];
#pragma unroll
    for (int j = 0; j < 8; j++) {
        accre[j] = (f32x4){0.f, 0.f, 0.f, 0.f};
        accim[j] = (f32x4){0.f, 0.f, 0.f, 0.f};
    }

    auto stage = [&](int buf, int kt) {
        {
            int row = tid >> 2, kc = (tid & 3) * 8;
            __builtin_amdgcn_global_load_lds(
                (AS1 const void*)(p1b + (size_t)(s0 + row) * 512 + kt + kc),
                (AS3 void*)(As[buf] + (size_t)(wave * 64) * 8), 16, 0, 0);
        }
#pragma unroll
        for (int j = 0; j < 2; j++) {
            int ch = j * 256 + tid;
            int row = ch >> 2, kc = (ch & 3) * 8;
            __builtin_amdgcn_global_load_lds(
                (AS1 const void*)(p1b + (size_t)row * 512 + kt + kc),
                (AS3 void*)(Bs1[buf] + (size_t)(j * 256 + wave * 64) * 8), 16, 0, 0);
            __builtin_amdgcn_global_load_lds(
                (AS1 const void*)(p2b + (size_t)row * 512 + kt + kc),
                (AS3 void*)(Bs2[buf] + (size_t)(j * 256 + wave * 64) * 8), 16, 0, 0);
        }
    };
    auto compute = [&](int buf) {
        bf16x8 afr = *(const bf16x8*)(As[buf] + (wave * 16 + lr) * 32 + quad * 8);
#pragma unroll
        for (int j = 0; j < 8; j++) {
            bf16x8 b1 = *(const bf16x8*)(Bs1[buf] + (j * 16 + lr) * 32 + quad * 8);
            accre[j] = __builtin_amdgcn_mfma_f32_16x16x32_bf16(afr, b1, accre[j], 0, 0, 0);
            bf16x8 b2 = *(const bf16x8*)(Bs2[buf] + (j * 16 + lr) * 32 + quad * 8);
            accim[j] = __builtin_amdgcn_mfma_f32_16x16x32_bf16(afr, b2, accim[j], 0, 0, 0);
        }
    };

    const int nt = 16;   // K=512
    stage(0, 0);
    __syncthreads();
    for (int t = 0; t < nt - 2; t += 2) {
        stage(1, (t + 1) << 5);
        compute(0);
        __syncthreads();
        stage(0, (t + 2) << 5);
        compute(1);
        __syncthreads();
    }
    stage(1, (nt - 1) << 5);
    compute(0);
    __syncthreads();
    compute(1);

    const float isq = 0.35355339059327373f;
    float ph_r[4], ph_c[8];
#pragma unroll
    for (int r = 0; r < 4; r++) ph_r[r] = phi[s0 + wave * 16 + quad * 4 + r];
#pragma unroll
    for (int j = 0; j < 8; j++) ph_c[j] = phi[j * 16 + lr];

#pragma unroll
    for (int r = 0; r < 4; r++) {
        float v[8];
        float mx = -1e30f;
#pragma unroll
        for (int j = 0; j < 8; j++) {
            float re = accre[j][r], im = accim[j][r];
            v[j] = (re * re + im * im) * isq + __cosf(ph_c[j] - ph_r[r]);
            mx = fmaxf(mx, v[j]);
        }
#pragma unroll
        for (int off = 1; off <= 8; off <<= 1) mx = fmaxf(mx, __shfl_xor(mx, off, 64));
        float sm = 0.f;
#pragma unroll
        for (int j = 0; j < 8; j++) { v[j] = __expf(v[j] - mx); sm += v[j]; }
#pragma unroll
        for (int off = 1; off <= 8; off <<= 1) sm += __shfl_xor(sm, off, 64);
        float inv = 1.f / sm;
        int srow = b * 128 + s0 + wave * 16 + quad * 4 + r;
#pragma unroll
        for (int j = 0; j < 8; j++) {
            float o = v[j] * inv;
            attn[(size_t)srow * 128 + j * 16 + lr] = o;
            attn_bf[(size_t)srow * 128 + j * 16 + lr] = f2bf(o);
        }
    }
}

// ---------------------------------------------------------------------------
extern "C" void kernel_launch(void* const* d_in, const int* in_sizes, int n_in,
                              void* d_out, int out_size, void* d_ws, size_t ws_size,
                              hipStream_t stream) {
    const float* X     = (const float*)d_in[0];
    const float* Wi    = (const float*)d_in[1];
    const float* bi    = (const float*)d_in[2];
    const float* Wv    = (const float*)d_in[3];
    const float* bv    = (const float*)d_in[4];
    const float* Wo    = (const float*)d_in[5];
    const float* bo    = (const float*)d_in[6];
    const float* theta = (const float*)d_in[7];
    const float* phi   = (const float*)d_in[8];

    float* y    = (float*)d_out;
    float* attn = y + (size_t)MM * EE;

    bf16s* Xb   = (bf16s*)d_ws;                      // 16384*1024
    bf16s* P1   = Xb  + (size_t)MM * EE;             // 16384*512
    bf16s* P2   = P1  + (size_t)MM * 512;            // 16384*512
    bf16s* Vtb  = P2  + (size_t)MM * 512;            // 128 * 1024*128
    bf16s* o2b  = Vtb + (size_t)MM * EE;             // 16384*1024
    bf16s* abf  = o2b + (size_t)MM * EE;             // 128*128*128
    bf16s* Wvt  = abf + (size_t)BB * SS * SS;        // 1024*1024
    bf16s* Wot  = Wvt + (size_t)EE * EE;             // 1024*1024
    float* Wit  = (float*)(Wot + (size_t)EE * EE);   // 8*1024 fp32 (32 KB)
    // v and Ubt overlap o2b (o2b written only after v/Ubt are dead)
    bf16s* v    = o2b;                               // 16384*256
    bf16s* Ubt  = o2b + (size_t)MM * DD;             // 512*256

    // Wi transpose (coalesced encode loads)
    wtrans_kernel<<<32, 256, 0, stream>>>(Wi, Wit);
    // encode: qin -> product state v (bf16) + Xb side-product
    encode_kernel<<<MM / 4, 256, 0, stream>>>(X, Wit, bi, Xb, v);
    // build circuit unitary (theta only)
    ubuild_kernel<<<64, 256, 0, stream>>>(theta, Ubt);
    // weight transposes
    transpose_conv_kernel<<<dim3(32, 32), 256, 0, stream>>>(Wv, Wvt, EE, EE);
    transpose_conv_kernel<<<dim3(32, 32), 256, 0, stream>>>(Wo, Wot, EE, EE);
    // psi = v @ Ubt^T -> P1, P2
    psi_gemm_kernel<<<dim3(MM / 128, 4), 256, 0, stream>>>(v, Ubt, P1, P2);
    // Vt_b = Wv^T @ X_b^T
    mfma_gemm<true, false><<<dim3(EE / 128, 1, BB), 256, 0, stream>>>(
        Wvt, Xb, nullptr, Vtb, EE, SS, EE,
        0, (long long)SS * EE, (long long)EE * SS);
    // attn (Gram via MFMA + softmax)
    attn_kernel<<<dim3(2, BB), 256, 0, stream>>>(P1, P2, phi, attn, abf);
    // o2_b = attn_b @ V_b + bv
    mfma_gemm<true, false><<<dim3(1, EE / 128, BB), 256, 0, stream>>>(
        abf, Vtb, bv, o2b, SS, EE, SS,
        (long long)SS * SS, (long long)EE * SS, (long long)SS * EE);
    // y = o2 @ Wo + bo  (SWAPXY: N fastest -> A-tile reuse across blocks)
    mfma_gemm<false, true><<<dim3(EE / 128, MM / 128, 1), 256, 0, stream>>>(
        o2b, Wot, bo, y, MM, EE, EE, 0, 0, 0);
}

// Round 3
// 333.798 us; speedup vs baseline: 1.0710x; 1.0555x over previous
//
#include <hip/hip_runtime.h>
#include <hip/hip_bf16.h>

#define BB 128
#define SS 128
#define EE 1024
#define NQ 8
#define DD 256
#define LL 4
#define MM (BB*SS)

typedef unsigned short bf16s;
typedef __attribute__((ext_vector_type(8))) short bf16x8;
typedef __attribute__((ext_vector_type(4))) float f32x4;

#define AS1 __attribute__((address_space(1)))
#define AS3 __attribute__((address_space(3)))

__device__ __forceinline__ unsigned short f2bf(float x) {
    unsigned u = __float_as_uint(x);
    u += 0x7fffu + ((u >> 16) & 1u);
    return (unsigned short)(u >> 16);
}

// ---------------------------------------------------------------------------
// fp32 RxC -> bf16 CxR transpose-convert (weights)
// ---------------------------------------------------------------------------
__global__ __launch_bounds__(256) void transpose_conv_kernel(
    const float* __restrict__ in, bf16s* __restrict__ out, int R, int C)
{
    __shared__ float t[32][33];
    int bx = blockIdx.x * 32, by = blockIdx.y * 32;
    int lx = threadIdx.x & 31, ly = threadIdx.x >> 5;
#pragma unroll
    for (int i = 0; i < 32; i += 8)
        t[ly + i][lx] = in[(size_t)(by + ly + i) * C + bx + lx];
    __syncthreads();
#pragma unroll
    for (int i = 0; i < 32; i += 8)
        out[(size_t)(bx + ly + i) * R + by + lx] = f2bf(t[lx][ly + i]);
}

// ---------------------------------------------------------------------------
// Wi[1024][8] -> Wit[8][1024] fp32 (tiny; enables coalesced encode loads)
// ---------------------------------------------------------------------------
__global__ __launch_bounds__(256) void wtrans_kernel(
    const float* __restrict__ Wi, float* __restrict__ Wit)
{
    int g = blockIdx.x * 256 + threadIdx.x;   // 0..8191
    int k = g >> 3, j = g & 7;
    Wit[j * 1024 + k] = Wi[g];
}

// ---------------------------------------------------------------------------
// encode: qin = X@Wi+bi; product state v (bf16); Xb = bf16(X) side-product.
// One wave per sample row. float4-vectorized (16B/lane) global loads.
// ---------------------------------------------------------------------------
__global__ __launch_bounds__(256) void encode_kernel(
    const float* __restrict__ X, const float* __restrict__ Wit,
    const float* __restrict__ bi,
    bf16s* __restrict__ Xb, bf16s* __restrict__ v)
{
    const int lane = threadIdx.x & 63;
    const int wid  = threadIdx.x >> 6;
    const int row  = blockIdx.x * 4 + wid;

    const f32x4* xr4 = (const f32x4*)(X + (size_t)row * EE);
    ushort4* xbr4 = (ushort4*)(Xb + (size_t)row * EE);

    float acc[NQ];
#pragma unroll
    for (int j = 0; j < NQ; j++) acc[j] = 0.f;

#pragma unroll
    for (int t = 0; t < 4; t++) {
        int k4 = t * 64 + lane;          // float4 index within the row
        f32x4 x = xr4[k4];
        ushort4 xb;
        xb.x = f2bf(x[0]); xb.y = f2bf(x[1]);
        xb.z = f2bf(x[2]); xb.w = f2bf(x[3]);
        xbr4[k4] = xb;
#pragma unroll
        for (int j = 0; j < NQ; j++) {
            f32x4 w = ((const f32x4*)(Wit + j * 1024))[k4];
            acc[j] += x[0]*w[0] + x[1]*w[1] + x[2]*w[2] + x[3]*w[3];
        }
    }
    float qin[NQ];
#pragma unroll
    for (int j = 0; j < NQ; j++) {
        float s = acc[j];
#pragma unroll
        for (int off = 32; off >= 1; off >>= 1) s += __shfl_xor(s, off, 64);
        qin[j] = s + bi[j];
    }

    // product state: amp[idx] = prod_b (bit_b(idx) ? sin : cos)(qin[7-b]/2)
    float cs[NQ], sn[NQ];
#pragma unroll
    for (int q = 0; q < NQ; q++) __sincosf(0.5f * qin[q], &sn[q], &cs[q]);

    float common = 1.f;
#pragma unroll
    for (int b = 2; b < 8; b++) {
        int q = 7 - b;
        common *= ((lane >> (b - 2)) & 1) ? sn[q] : cs[q];
    }
    // cc bit0 -> qubit 7, bit1 -> qubit 6
    float a0 = common * cs[6] * cs[7];
    float a1 = common * cs[6] * sn[7];
    float a2 = common * sn[6] * cs[7];
    float a3 = common * sn[6] * sn[7];
    ushort4 vo;
    vo.x = f2bf(a0); vo.y = f2bf(a1); vo.z = f2bf(a2); vo.w = f2bf(a3);
    ((ushort4*)(v + (size_t)row * DD))[lane] = vo;
}

// ---------------------------------------------------------------------------
// ubuild: simulate the theta-circuit on all 256 basis states -> Ubt bf16.
// Ubt[n][j] (n<256: U_re[n][j]; n>=256: U_im[n-256][j]), j = basis column.
// ---------------------------------------------------------------------------
__global__ __launch_bounds__(256) void ubuild_kernel(
    const float* __restrict__ theta, bf16s* __restrict__ Ubt)
{
    const int lane = threadIdx.x & 63;
    const int wid  = threadIdx.x >> 6;
    const int col  = blockIdx.x * 4 + wid;   // 0..255

    float sr[4], si[4];
#pragma unroll
    for (int c = 0; c < 4; c++) { sr[c] = 0.f; si[c] = 0.f; }
    if (lane == (col >> 2)) sr[col & 3] = 1.f;

    auto apply_ry = [&](int b, float th) {
        float s, c;
        __sincosf(0.5f * th, &s, &c);
        if (b >= 2) {
            int lb = b - 2;
            int bit = (lane >> lb) & 1;
            float sgn = bit ? s : -s;
#pragma unroll
            for (int cc = 0; cc < 4; cc++) {
                float pr = __shfl_xor(sr[cc], 1 << lb, 64);
                float pi = __shfl_xor(si[cc], 1 << lb, 64);
                sr[cc] = c * sr[cc] + sgn * pr;
                si[cc] = c * si[cc] + sgn * pi;
            }
        } else {
            int m = 1 << b;
            float tr[4], ti[4];
#pragma unroll
            for (int cc = 0; cc < 4; cc++) { tr[cc] = sr[cc]; ti[cc] = si[cc]; }
#pragma unroll
            for (int cc = 0; cc < 4; cc++) {
                int bit = (cc >> b) & 1;
                float sgn = bit ? s : -s;
                sr[cc] = c * tr[cc] + sgn * tr[cc ^ m];
                si[cc] = c * ti[cc] + sgn * ti[cc ^ m];
            }
        }
    };
    auto apply_rz = [&](int b, float th) {
        float sz, cr;
        __sincosf(0.5f * th, &sz, &cr);
#pragma unroll
        for (int cc = 0; cc < 4; cc++) {
            int bit = (b >= 2) ? ((lane >> (b - 2)) & 1) : ((cc >> b) & 1);
            float ci = bit ? sz : -sz;
            float r = sr[cc], i = si[cc];
            sr[cc] = r * cr - i * ci;
            si[cc] = r * ci + i * cr;
        }
    };
    auto apply_cnot = [&](int bc, int bt) {
        float pr[4], pi[4];
        if (bt >= 2) {
            int m = 1 << (bt - 2);
#pragma unroll
            for (int cc = 0; cc < 4; cc++) {
                pr[cc] = __shfl_xor(sr[cc], m, 64);
                pi[cc] = __shfl_xor(si[cc], m, 64);
            }
        } else {
            int m = 1 << bt;
#pragma unroll
            for (int cc = 0; cc < 4; cc++) {
                pr[cc] = sr[cc ^ m];
                pi[cc] = si[cc ^ m];
            }
        }
#pragma unroll
        for (int cc = 0; cc < 4; cc++) {
            int ctrl = (bc >= 2) ? ((lane >> (bc - 2)) & 1) : ((cc >> bc) & 1);
            sr[cc] = ctrl ? pr[cc] : sr[cc];
            si[cc] = ctrl ? pi[cc] : si[cc];
        }
    };

#pragma unroll
    for (int l = 0; l < LL; l++) {
#pragma unroll
        for (int q = 0; q < NQ; q++) {
            apply_ry(7 - q, theta[(l * NQ + q) * 2 + 0]);
            apply_rz(7 - q, theta[(l * NQ + q) * 2 + 1]);
        }
#pragma unroll
        for (int q = 0; q < NQ; q++) {
            int t = (q + 1) & 7;
            apply_cnot(7 - q, 7 - t);
        }
    }

#pragma unroll
    for (int cc = 0; cc < 4; cc++) {
        int i = lane * 4 + cc;
        Ubt[(size_t)i * DD + col]         = f2bf(sr[cc]);
        Ubt[(size_t)(i + DD) * DD + col]  = f2bf(si[cc]);
    }
}

// ---------------------------------------------------------------------------
// psi_gemm: C[s][n] = v[s][:] . Ubt[n][:]  (M=16384, N=512, K=256)
// 2-phase double-buffered pipeline. Epilogue writes P1/P2.
// ---------------------------------------------------------------------------
__global__ __launch_bounds__(256) void psi_gemm_kernel(
    const bf16s* __restrict__ A, const bf16s* __restrict__ Bt,
    bf16s* __restrict__ P1, bf16s* __restrict__ P2)
{
    __shared__ bf16s As[2][128 * 32];
    __shared__ bf16s Bs[2][128 * 32];

    const int tid  = threadIdx.x;
    const int wave = tid >> 6, lane = tid & 63;
    const int quad = lane >> 4, lr = lane & 15;
    const int wm = (wave >> 1) * 64, wn = (wave & 1) * 64;
    const int m0 = blockIdx.x * 128, n0 = blockIdx.y * 128;
    const int K = DD, N = 2 * DD;

    f32x4 acc[4][4];
#pragma unroll
    for (int i = 0; i < 4; i++)
#pragma unroll
        for (int j = 0; j < 4; j++) acc[i][j] = (f32x4){0.f, 0.f, 0.f, 0.f};

    auto stage = [&](int buf, int kt) {
#pragma unroll
        for (int j = 0; j < 2; j++) {
            int ch = j * 256 + tid;
            int row = ch >> 2, kc = (ch & 3) * 8;
            __builtin_amdgcn_global_load_lds(
                (AS1 const void*)(A + (size_t)(m0 + row) * K + kt + kc),
                (AS3 void*)(As[buf] + (size_t)(j * 256 + wave * 64) * 8), 16, 0, 0);
            __builtin_amdgcn_global_load_lds(
                (AS1 const void*)(Bt + (size_t)(n0 + row) * K + kt + kc),
                (AS3 void*)(Bs[buf] + (size_t)(j * 256 + wave * 64) * 8), 16, 0, 0);
        }
    };
    auto compute = [&](int buf) {
        bf16x8 af[4], bfr[4];
#pragma unroll
        for (int i = 0; i < 4; i++)
            af[i] = *(const bf16x8*)(As[buf] + (wm + i * 16 + lr) * 32 + quad * 8);
#pragma unroll
        for (int j = 0; j < 4; j++)
            bfr[j] = *(const bf16x8*)(Bs[buf] + (wn + j * 16 + lr) * 32 + quad * 8);
#pragma unroll
        for (int i = 0; i < 4; i++)
#pragma unroll
            for (int j = 0; j < 4; j++)
                acc[i][j] = __builtin_amdgcn_mfma_f32_16x16x32_bf16(
                    af[i], bfr[j], acc[i][j], 0, 0, 0);
    };

    const int nt = K >> 5;   // 8 (even)
    stage(0, 0);
    __syncthreads();
    for (int t = 0; t < nt - 2; t += 2) {
        stage(1, (t + 1) << 5);
        compute(0);
        __syncthreads();
        stage(0, (t + 2) << 5);
        compute(1);
        __syncthreads();
    }
    stage(1, (nt - 1) << 5);
    compute(0);
    __syncthreads();
    compute(1);

#pragma unroll
    for (int i = 0; i < 4; i++) {
        int row0 = m0 + wm + i * 16 + quad * 4;
#pragma unroll
        for (int j = 0; j < 4; j++) {
            int col = n0 + wn + j * 16 + lr;
            int c2  = (col < DD) ? (col + DD) : (col - DD);
            float sgn = (col < DD) ? -1.f : 1.f;
#pragma unroll
            for (int r = 0; r < 4; r++) {
                float val = acc[i][j][r];
                P1[(size_t)(row0 + r) * N + col] = f2bf(val);
                P2[(size_t)(row0 + r) * N + c2] = f2bf(sgn * val);
            }
        }
    }
}

// ---------------------------------------------------------------------------
// MFMA bf16 GEMM: C[M][N] = A[M][K] @ Bt[N][K]^T (+bias[col]).
// 2-phase double-buffered pipeline. 1D grid with bijective XCD chunking:
// hardware puts block bid on XCD bid%8; remap so each XCD owns a contiguous
// work chunk (n-fastest) -> A-tile shared by n-blocks inside ONE XCD's L2.
// Work order: w = (z * nm + m) * nn + n.
// ---------------------------------------------------------------------------
template<bool OUT_BF16>
__global__ __launch_bounds__(256) void mfma_gemm(
    const bf16s* __restrict__ A, const bf16s* __restrict__ Bt,
    const float* __restrict__ bias, void* __restrict__ Cv,
    int M, int N, int K, int nm, int nn,
    long long sA, long long sB, long long sC)
{
    __shared__ bf16s As[2][128 * 32];
    __shared__ bf16s Bs[2][128 * 32];

    const int tid  = threadIdx.x;
    const int wave = tid >> 6, lane = tid & 63;
    const int quad = lane >> 4, lr = lane & 15;
    const int wm = (wave >> 1) * 64, wn = (wave & 1) * 64;

    // bijective XCD chunk swizzle (m204): xcd k -> work chunk k
    const int nwg = gridDim.x;
    const int q = nwg >> 3, r = nwg & 7;
    const int xcd = blockIdx.x & 7, idx = blockIdx.x >> 3;
    const int w = (xcd < r ? xcd * (q + 1) : r * (q + 1) + (xcd - r) * q) + idx;
    const int n_t = w % nn;
    const int m_t = (w / nn) % nm;
    const int z   = w / (nn * nm);
    const int m0 = m_t * 128, n0 = n_t * 128;

    A  += (size_t)z * sA;
    Bt += (size_t)z * sB;

    f32x4 acc[4][4];
#pragma unroll
    for (int i = 0; i < 4; i++)
#pragma unroll
        for (int j = 0; j < 4; j++) acc[i][j] = (f32x4){0.f, 0.f, 0.f, 0.f};

    auto stage = [&](int buf, int kt) {
#pragma unroll
        for (int j = 0; j < 2; j++) {
            int ch = j * 256 + tid;
            int row = ch >> 2, kc = (ch & 3) * 8;
            __builtin_amdgcn_global_load_lds(
                (AS1 const void*)(A + (size_t)(m0 + row) * K + kt + kc),
                (AS3 void*)(As[buf] + (size_t)(j * 256 + wave * 64) * 8), 16, 0, 0);
            __builtin_amdgcn_global_load_lds(
                (AS1 const void*)(Bt + (size_t)(n0 + row) * K + kt + kc),
                (AS3 void*)(Bs[buf] + (size_t)(j * 256 + wave * 64) * 8), 16, 0, 0);
        }
    };
    auto compute = [&](int buf) {
        bf16x8 af[4], bfr[4];
#pragma unroll
        for (int i = 0; i < 4; i++)
            af[i] = *(const bf16x8*)(As[buf] + (wm + i * 16 + lr) * 32 + quad * 8);
#pragma unroll
        for (int j = 0; j < 4; j++)
            bfr[j] = *(const bf16x8*)(Bs[buf] + (wn + j * 16 + lr) * 32 + quad * 8);
#pragma unroll
        for (int i = 0; i < 4; i++)
#pragma unroll
            for (int j = 0; j < 4; j++)
                acc[i][j] = __builtin_amdgcn_mfma_f32_16x16x32_bf16(
                    af[i], bfr[j], acc[i][j], 0, 0, 0);
    };

    const int nt = K >> 5;   // all call sites: even, >= 4
    stage(0, 0);
    __syncthreads();
    for (int t = 0; t < nt - 2; t += 2) {
        stage(1, (t + 1) << 5);
        compute(0);
        __syncthreads();
        stage(0, (t + 2) << 5);
        compute(1);
        __syncthreads();
    }
    stage(1, (nt - 1) << 5);
    compute(0);
    __syncthreads();
    compute(1);

    float* Cf = (float*)Cv + (size_t)z * sC;
    bf16s* Cb = (bf16s*)Cv + (size_t)z * sC;
#pragma unroll
    for (int i = 0; i < 4; i++) {
        int row0 = m0 + wm + i * 16 + quad * 4;
#pragma unroll
        for (int j = 0; j < 4; j++) {
            int col = n0 + wn + j * 16 + lr;
            float bb = bias ? bias[col] : 0.f;
#pragma unroll
            for (int r = 0; r < 4; r++) {
                float v = acc[i][j][r] + bb;
                if (OUT_BF16) Cb[(size_t)(row0 + r) * N + col] = f2bf(v);
                else          Cf[(size_t)(row0 + r) * N + col] = v;
            }
        }
    }
}

// ---------------------------------------------------------------------------
// attn: MFMA Gram + fused softmax. 2-phase double-buffered pipeline.
// ---------------------------------------------------------------------------
__global__ __launch_bounds__(256) void attn_kernel(
    const bf16s* __restrict__ P1, const bf16s* __restrict__ P2,
    const float* __restrict__ phi,
    float* __restrict__ attn, bf16s* __restrict__ attn_bf)
{
    __shared__ bf16s As [2][64 * 32];
    __shared__ bf16s Bs1[2][128 * 32];
    __shared__ bf16s Bs2[2][128 * 32];

    const int tid  = threadIdx.x;
    const int wave = tid >> 6, lane = tid & 63;
    const int quad = lane >> 4, lr = lane & 15;
    const int b = blockIdx.y;
    const int s0 = blockIdx.x * 64;
    const bf16s* p1b = P1 + (size_t)b * 128 * 512;
    const bf16s* p2b = P2 + (size_t)b * 128 * 512;

    f32x4 accre[8], accim[8];
#pragma unroll
    for (int j = 0; j < 8; j++) {
        accre[j] = (f32x4){0.f, 0.f, 0.f, 0.f};
        accim[j] = (f32x4){0.f, 0.f, 0.f, 0.f};
    }

    auto stage = [&](int buf, int kt) {
        {
            int row = tid >> 2, kc = (tid & 3) * 8;
            __builtin_amdgcn_global_load_lds(
                (AS1 const void*)(p1b + (size_t)(s0 + row) * 512 + kt + kc),
                (AS3 void*)(As[buf] + (size_t)(wave * 64) * 8), 16, 0, 0);
        }
#pragma unroll
        for (int j = 0; j < 2; j++) {
            int ch = j * 256 + tid;
            int row = ch >> 2, kc = (ch & 3) * 8;
            __builtin_amdgcn_global_load_lds(
                (AS1 const void*)(p1b + (size_t)row * 512 + kt + kc),
                (AS3 void*)(Bs1[buf] + (size_t)(j * 256 + wave * 64) * 8), 16, 0, 0);
            __builtin_amdgcn_global_load_lds(
                (AS1 const void*)(p2b + (size_t)row * 512 + kt + kc),
                (AS3 void*)(Bs2[buf] + (size_t)(j * 256 + wave * 64) * 8), 16, 0, 0);
        }
    };
    auto compute = [&](int buf) {
        bf16x8 afr = *(const bf16x8*)(As[buf] + (wave * 16 + lr) * 32 + quad * 8);
#pragma unroll
        for (int j = 0; j < 8; j++) {
            bf16x8 b1 = *(const bf16x8*)(Bs1[buf] + (j * 16 + lr) * 32 + quad * 8);
            accre[j] = __builtin_amdgcn_mfma_f32_16x16x32_bf16(afr, b1, accre[j], 0, 0, 0);
            bf16x8 b2 = *(const bf16x8*)(Bs2[buf] + (j * 16 + lr) * 32 + quad * 8);
            accim[j] = __builtin_amdgcn_mfma_f32_16x16x32_bf16(afr, b2, accim[j], 0, 0, 0);
        }
    };

    const int nt = 16;   // K=512
    stage(0, 0);
    __syncthreads();
    for (int t = 0; t < nt - 2; t += 2) {
        stage(1, (t + 1) << 5);
        compute(0);
        __syncthreads();
        stage(0, (t + 2) << 5);
        compute(1);
        __syncthreads();
    }
    stage(1, (nt - 1) << 5);
    compute(0);
    __syncthreads();
    compute(1);

    const float isq = 0.35355339059327373f;
    float ph_r[4], ph_c[8];
#pragma unroll
    for (int r = 0; r < 4; r++) ph_r[r] = phi[s0 + wave * 16 + quad * 4 + r];
#pragma unroll
    for (int j = 0; j < 8; j++) ph_c[j] = phi[j * 16 + lr];

#pragma unroll
    for (int r = 0; r < 4; r++) {
        float v[8];
        float mx = -1e30f;
#pragma unroll
        for (int j = 0; j < 8; j++) {
            float re = accre[j][r], im = accim[j][r];
            v[j] = (re * re + im * im) * isq + __cosf(ph_c[j] - ph_r[r]);
            mx = fmaxf(mx, v[j]);
        }
#pragma unroll
        for (int off = 1; off <= 8; off <<= 1) mx = fmaxf(mx, __shfl_xor(mx, off, 64));
        float sm = 0.f;
#pragma unroll
        for (int j = 0; j < 8; j++) { v[j] = __expf(v[j] - mx); sm += v[j]; }
#pragma unroll
        for (int off = 1; off <= 8; off <<= 1) sm += __shfl_xor(sm, off, 64);
        float inv = 1.f / sm;
        int srow = b * 128 + s0 + wave * 16 + quad * 4 + r;
#pragma unroll
        for (int j = 0; j < 8; j++) {
            float o = v[j] * inv;
            attn[(size_t)srow * 128 + j * 16 + lr] = o;
            attn_bf[(size_t)srow * 128 + j * 16 + lr] = f2bf(o);
        }
    }
}

// ---------------------------------------------------------------------------
extern "C" void kernel_launch(void* const* d_in, const int* in_sizes, int n_in,
                              void* d_out, int out_size, void* d_ws, size_t ws_size,
                              hipStream_t stream) {
    const float* X     = (const float*)d_in[0];
    const float* Wi    = (const float*)d_in[1];
    const float* bi    = (const float*)d_in[2];
    const float* Wv    = (const float*)d_in[3];
    const float* bv    = (const float*)d_in[4];
    const float* Wo    = (const float*)d_in[5];
    const float* bo    = (const float*)d_in[6];
    const float* theta = (const float*)d_in[7];
    const float* phi   = (const float*)d_in[8];

    float* y    = (float*)d_out;
    float* attn = y + (size_t)MM * EE;

    bf16s* Xb   = (bf16s*)d_ws;                      // 16384*1024
    bf16s* P1   = Xb  + (size_t)MM * EE;             // 16384*512
    bf16s* P2   = P1  + (size_t)MM * 512;            // 16384*512
    bf16s* Vtb  = P2  + (size_t)MM * 512;            // 128 * 1024*128
    bf16s* o2b  = Vtb + (size_t)MM * EE;             // 16384*1024
    bf16s* abf  = o2b + (size_t)MM * EE;             // 128*128*128
    bf16s* Wvt  = abf + (size_t)BB * SS * SS;        // 1024*1024
    bf16s* Wot  = Wvt + (size_t)EE * EE;             // 1024*1024
    float* Wit  = (float*)(Wot + (size_t)EE * EE);   // 8*1024 fp32 (32 KB)
    // v and Ubt overlap o2b (o2b written only after v/Ubt are dead)
    bf16s* v    = o2b;                               // 16384*256
    bf16s* Ubt  = o2b + (size_t)MM * DD;             // 512*256

    // Wi transpose (coalesced encode loads)
    wtrans_kernel<<<32, 256, 0, stream>>>(Wi, Wit);
    // encode: qin -> product state v (bf16) + Xb side-product
    encode_kernel<<<MM / 4, 256, 0, stream>>>(X, Wit, bi, Xb, v);
    // build circuit unitary (theta only)
    ubuild_kernel<<<64, 256, 0, stream>>>(theta, Ubt);
    // weight transposes
    transpose_conv_kernel<<<dim3(32, 32), 256, 0, stream>>>(Wv, Wvt, EE, EE);
    transpose_conv_kernel<<<dim3(32, 32), 256, 0, stream>>>(Wo, Wot, EE, EE);
    // psi = v @ Ubt^T -> P1, P2
    psi_gemm_kernel<<<dim3(MM / 128, 4), 256, 0, stream>>>(v, Ubt, P1, P2);
    // Vt_b = Wv^T @ X_b^T   (w = z*8 + m; each XCD gets 16 batches, Wvt L2-res)
    mfma_gemm<true><<<1024, 256, 0, stream>>>(
        Wvt, Xb, nullptr, Vtb, EE, SS, EE, /*nm*/8, /*nn*/1,
        0, (long long)SS * EE, (long long)EE * SS);
    // attn (Gram via MFMA + softmax)
    attn_kernel<<<dim3(2, BB), 256, 0, stream>>>(P1, P2, phi, attn, abf);
    // o2_b = attn_b @ V_b + bv  (w = z*8 + n; abf L2-resident per XCD)
    mfma_gemm<true><<<1024, 256, 0, stream>>>(
        abf, Vtb, bv, o2b, SS, EE, SS, /*nm*/1, /*nn*/8,
        (long long)SS * SS, (long long)EE * SS, (long long)SS * EE);
    // y = o2 @ Wo + bo  (w = m*8 + n; A-tile shared within one XCD's L2)
    mfma_gemm<false><<<1024, 256, 0, stream>>>(
        o2b, Wot, bo, y, MM, EE, EE, /*nm*/128, /*nn*/8, 0, 0, 0);
}